// Round 6
// baseline (737.468 us; speedup 1.0000x reference)
//
#include <hip/hip_runtime.h>
#include <hip/hip_bf16.h>

// Problem constants
#define BB 64     // batch
#define NT 128    // text tokens
#define NV 256    // visual tokens
#define DD 512    // feature dim (bytes per row in fp8)
#define BKB 128   // K-chunk in bytes: one 16x16x128 f8f6f4 k-step
#define EPSF 1e-7f

typedef __attribute__((ext_vector_type(8))) int i32x8;
typedef __attribute__((ext_vector_type(4))) int i32x4;
typedef __attribute__((ext_vector_type(4))) float f32x4;

__device__ __forceinline__ void glds16(const uchar* g, uchar* l) {
    __builtin_amdgcn_global_load_lds(
        (const __attribute__((address_space(1))) unsigned int*)g,
        (__attribute__((address_space(3))) unsigned int*)l, 16, 0, 0);
}

// ---------------------------------------------------------------------------
// Kernel 1: L2-normalize rows, write fp8 e4m3 (OCP). Wave per row.
// ---------------------------------------------------------------------------
__global__ __launch_bounds__(256) void k_normalize(
    const float* __restrict__ tf, const float* __restrict__ vf,
    uchar* __restrict__ tn, uchar* __restrict__ vn,
    float* __restrict__ reg_sum) {
    if (blockIdx.x == 0 && threadIdx.x == 0) *reg_sum = 0.0f;
    const int w = threadIdx.x >> 6, l = threadIdx.x & 63;
    const int row = blockIdx.x * 4 + w;
    const float* src;
    uchar* dst;
    if (row < BB * NT) {
        src = tf + (size_t)row * DD;
        dst = tn + (size_t)row * DD;
    } else {
        int r = row - BB * NT;
        src = vf + (size_t)r * DD;
        dst = vn + (size_t)r * DD;
    }
    float4 x0 = ((const float4*)src)[l * 2];
    float4 x1 = ((const float4*)src)[l * 2 + 1];
    float ss = x0.x * x0.x + x0.y * x0.y + x0.z * x0.z + x0.w * x0.w
             + x1.x * x1.x + x1.y * x1.y + x1.z * x1.z + x1.w * x1.w;
    #pragma unroll
    for (int off = 32; off; off >>= 1) ss += __shfl_xor(ss, off, 64);
    float scale = 1.0f / fmaxf(sqrtf(ss), 1e-12f);
    int p0 = __builtin_amdgcn_cvt_pk_fp8_f32(x0.x * scale, x0.y * scale, 0, 0);
    p0 = __builtin_amdgcn_cvt_pk_fp8_f32(x0.z * scale, x0.w * scale, p0, 1);
    int p1 = __builtin_amdgcn_cvt_pk_fp8_f32(x1.x * scale, x1.y * scale, 0, 0);
    p1 = __builtin_amdgcn_cvt_pk_fp8_f32(x1.z * scale, x1.w * scale, p1, 1);
    ((uint2*)dst)[l] = make_uint2((unsigned)p0, (unsigned)p1);
}

// ---------------------------------------------------------------------------
// Kernel 2: 128x256 tile per (i,j) pair (round-4 verified geometry), with:
//   * T staged via global_load_lds into a 2x16KB double buffer (rotation
//     swizzle, verified) -- T enjoys 4x cross-wave reuse in LDS.
//   * V fragments loaded DIRECTLY global->VGPR (two global_load_dwordx4 per
//     fragment at vrow*512 + kk + q*32 -- bit-identical register contents to
//     the old LDS path; V is L2-resident: 1 MB/XCD under the round-3
//     verified XCD mapping). Removes 32KB/step of LDS DMA + 256KB/block of
//     ds_read -> LDS pipe drops below the MFMA pipe.
//   * LDS now 34KB -> 2 blocks/CU at 128 VGPRs -> 4 waves/SIMD (was 2).
//     __launch_bounds__(512,4) pins the 128-reg budget the allocator was
//     choosing anyway (proven rounds 2/3/5: it never grants more).
// Schedule: prefetch-before-compute + one __syncthreads per K-step
// (correctness-verified rounds 2-5, absmax 0.0).
// ---------------------------------------------------------------------------
__global__ __launch_bounds__(512, 4) void k_gemm(
    const uchar* __restrict__ tn, const uchar* __restrict__ vn,
    const int* __restrict__ mask,
    float* __restrict__ clip_sims, float* __restrict__ reg_sum) {
    __shared__ uchar sT0[NT * BKB];   // 16 KB
    __shared__ uchar sT1[NT * BKB];   // 16 KB
    __shared__ float maxbuf[NT][4];   // row-max partials per wave col-group
    __shared__ float redw[8];
    __shared__ float c0[2], c1[2];

    // XCD-aware mapping (bijective over 4096 blocks), round-3/4 verified
    // locality: j fast over 8 private visual batches per XCD (V stays
    // L2-resident), i slow.
    const int bid = blockIdx.x;
    const int xcd = bid & 7;
    const int seq = bid >> 3;
    const int i = seq >> 3;              // text batch (0..63)
    const int j = xcd * 8 + (seq & 7);   // visual batch (0..63)

    const int tid = threadIdx.x;
    const int l = tid & 63, w = tid >> 6;
    const int wr = w >> 2, wc = w & 3;      // wave row-group (0..1), col-group (0..3)
    const int m15 = l & 15, q = l >> 4;

    const uchar* tbase = tn + (size_t)i * NT * DD;
    const uchar* vbase = vn + (size_t)j * NV * DD;

    // T staging: 16B unit f -> row r = f>>3, phys granule p = f&7 holds
    // logical granule g = (p - r) & 7.  src = r*DD + kk + g*16.
    int t_off[2];
    #pragma unroll
    for (int s = 0; s < 2; ++s) {
        int f = s * 512 + tid;
        int r = f >> 3, p = f & 7, g = (p - r) & 7;
        t_off[s] = r * DD + g * 16;
    }

    // A-fragment LDS read addresses (rotation-mirrored, verified):
    // lane holds k = q*32..q*32+31 of row wr*64+rt*16+m15.
    int a_b0[4], a_b1[4];
    #pragma unroll
    for (int rt = 0; rt < 4; ++rt) {
        int row = wr * 64 + rt * 16 + m15;
        a_b0[rt] = row * BKB + (((2 * q + row) & 7) * 16);
        a_b1[rt] = row * BKB + (((2 * q + 1 + row) & 7) * 16);
    }

    // B-fragment global base: row wc*64 + ct*16 + m15, k-bytes q*32..+31.
    // ct adds a static 16*DD; kk added per step.
    const uchar* vptr = vbase + (size_t)((wc * 64 + m15) * DD + q * 32);

    f32x4 acc[4][4];
    #pragma unroll
    for (int rt = 0; rt < 4; ++rt)
        #pragma unroll
        for (int ct = 0; ct < 4; ++ct) acc[rt][ct] = (f32x4){0.f, 0.f, 0.f, 0.f};

    auto stage = [&](uchar* dT, int kk) {
        #pragma unroll
        for (int s = 0; s < 2; ++s)
            glds16(tbase + t_off[s] + kk, dT + (s * 512 + tid) * 16);
    };
    auto compute = [&](const uchar* bT, int kk) {
        i32x8 bf[4];
        #pragma unroll
        for (int ct = 0; ct < 4; ++ct) {
            const uchar* vp = vptr + ct * (16 * DD) + kk;
            i32x4 lo = *(const i32x4*)(vp);
            i32x4 hi = *(const i32x4*)(vp + 16);
            bf[ct] = (i32x8){lo.x, lo.y, lo.z, lo.w, hi.x, hi.y, hi.z, hi.w};
        }
        #pragma unroll
        for (int rt = 0; rt < 4; ++rt) {
            i32x4 lo = *(const i32x4*)(bT + a_b0[rt]);
            i32x4 hi = *(const i32x4*)(bT + a_b1[rt]);
            i32x8 a = (i32x8){lo.x, lo.y, lo.z, lo.w, hi.x, hi.y, hi.z, hi.w};
            #pragma unroll
            for (int ct = 0; ct < 4; ++ct)
                acc[rt][ct] = __builtin_amdgcn_mfma_scale_f32_16x16x128_f8f6f4(
                    a, bf[ct], acc[rt][ct],
                    0 /*A fmt=fp8*/, 0 /*B fmt=fp8*/,
                    0, 127 /*scaleA=1.0*/, 0, 127 /*scaleB=1.0*/);
        }
    };

    // Pipelined schedule: stage(next T) issued before compute(cur); one
    // barrier per K-step fences the prefetch drain and the buffer swap.
    stage(sT0, 0);
    __syncthreads();

    stage(sT1, 1 * BKB);
    compute(sT0, 0);
    __syncthreads();

    stage(sT0, 2 * BKB);
    compute(sT1, 1 * BKB);
    __syncthreads();

    stage(sT1, 3 * BKB);
    compute(sT0, 2 * BKB);
    __syncthreads();

    compute(sT1, 3 * BKB);

    // Epilogue 1: reg partial = sum of min(s,0)^2 over this lane's 64 values.
    float rp = 0.0f;
    #pragma unroll
    for (int rt = 0; rt < 4; ++rt)
        #pragma unroll
        for (int ct = 0; ct < 4; ++ct)
            #pragma unroll
            for (int r = 0; r < 4; ++r) {
                float m = fminf(acc[rt][ct][r], 0.0f);
                rp = fmaf(m, m, rp);
            }

    // Epilogue 2: row max. C/D layout: col = lane&15, row = q*4 + reg.
    #pragma unroll
    for (int rt = 0; rt < 4; ++rt)
        #pragma unroll
        for (int r = 0; r < 4; ++r) {
            float m = acc[rt][0][r];
            #pragma unroll
            for (int ct = 1; ct < 4; ++ct) m = fmaxf(m, acc[rt][ct][r]);
            #pragma unroll
            for (int msk = 1; msk < 16; msk <<= 1)
                m = fmaxf(m, __shfl_xor(m, msk, 64));
            if (m15 == 0)
                maxbuf[wr * 64 + rt * 16 + q * 4 + r][wc] = m;
        }

    #pragma unroll
    for (int off = 32; off; off >>= 1) rp += __shfl_down(rp, off, 64);
    if (l == 0) redw[w] = rp;
    __syncthreads();

    // Fused clip: masked mean of row maxes over the 128 text tokens.
    if (tid < NT) {
        float rm = fmaxf(fmaxf(maxbuf[tid][0], maxbuf[tid][1]),
                         fmaxf(maxbuf[tid][2], maxbuf[tid][3]));
        float mf = (float)mask[i * NT + tid];
        float v = rm * mf;
        #pragma unroll
        for (int off = 32; off; off >>= 1) {
            v += __shfl_down(v, off, 64);
            mf += __shfl_down(mf, off, 64);
        }
        if (l == 0) { c0[w] = v; c1[w] = mf; }
    }
    __syncthreads();
    if (tid == 0) {
        clip_sims[i * BB + j] = (c0[0] + c0[1]) / fmaxf(c1[0] + c1[1], EPSF);
        float s = 0.0f;
        #pragma unroll
        for (int x2 = 0; x2 < 8; ++x2) s += redw[x2];
        atomicAdd(reg_sum, s);
    }
}

// ---------------------------------------------------------------------------
// Kernel 3: final scalar loss. Single block, 256 threads.
// ---------------------------------------------------------------------------
__global__ __launch_bounds__(256) void k_loss(
    const float* __restrict__ clip_sims, const float* __restrict__ reg_sum,
    float* __restrict__ out) {
    __shared__ float sc[BB][BB + 1];
    __shared__ float lrow[BB], lcol[BB];
    int tid = threadIdx.x;
    for (int idx = tid; idx < BB * BB; idx += 256)
        sc[idx / BB][idx % BB] = clip_sims[idx];
    __syncthreads();
    if (tid < BB) {
        int i = tid;
        float m = sc[i][0];
        #pragma unroll
        for (int j = 1; j < BB; ++j) m = fmaxf(m, sc[i][j]);
        float s = 0.0f;
        #pragma unroll
        for (int j = 0; j < BB; ++j) s += expf(sc[i][j] - m);
        lrow[i] = m + logf(s) - sc[i][i];
    } else if (tid < 2 * BB) {
        int i = tid - BB;
        float m = sc[0][i];
        #pragma unroll
        for (int j = 1; j < BB; ++j) m = fmaxf(m, sc[j][i]);
        float s = 0.0f;
        #pragma unroll
        for (int j = 0; j < BB; ++j) s += expf(sc[j][i] - m);
        lcol[i] = m + logf(s) - sc[i][i];
    }
    __syncthreads();
    if (tid == 0) {
        float tot = 0.0f;
        for (int i = 0; i < BB; ++i) tot += lrow[i] + lcol[i];
        float contrastive = tot / (2.0f * BB);
        double denom = (double)BB * BB * NT * NV;  // 134217728
        float reg = 0.15f * (float)((double)reg_sum[0] / denom);
        out[0] = contrastive + reg;
    }
}

// ---------------------------------------------------------------------------
extern "C" void kernel_launch(void* const* d_in, const int* in_sizes, int n_in,
                              void* d_out, int out_size, void* d_ws, size_t ws_size,
                              hipStream_t stream) {
    const float* tf = (const float*)d_in[0];   // (B, NT, D) fp32
    const float* vf = (const float*)d_in[1];   // (B, NV, D) fp32
    const int* mask = (const int*)d_in[2];     // (B, NT) int32
    float* out = (float*)d_out;                // scalar fp32

    char* ws = (char*)d_ws;
    size_t tn_bytes = (size_t)BB * NT * DD;              // 4 MB fp8
    size_t vn_bytes = (size_t)BB * NV * DD;              // 8 MB fp8
    size_t cs_bytes = (size_t)BB * BB * sizeof(float);   // 16 KB

    uchar* tn = (uchar*)ws;
    uchar* vn = (uchar*)(ws + tn_bytes);
    float* clip_sims = (float*)(ws + tn_bytes + vn_bytes);
    float* reg_sum = (float*)(ws + tn_bytes + vn_bytes + cs_bytes);

    k_normalize<<<(BB * NT + BB * NV) / 4, 256, 0, stream>>>(tf, vf, tn, vn, reg_sum);
    k_gemm<<<BB * BB, 512, 0, stream>>>(tn, vn, mask, clip_sims, reg_sum);
    k_loss<<<1, 256, 0, stream>>>(clip_sims, reg_sum, out);
}

// Round 7
// 299.780 us; speedup vs baseline: 2.4600x; 2.4600x over previous
//
#include <hip/hip_runtime.h>
#include <hip/hip_bf16.h>

// Problem constants
#define BB 64     // batch
#define NT 128    // text tokens
#define NV 256    // visual tokens
#define DD 512    // feature dim (bytes per row in fp8)
#define BKB 128   // K-chunk in bytes: one 16x16x128 f8f6f4 k-step
#define EPSF 1e-7f

typedef __attribute__((ext_vector_type(8))) int i32x8;
typedef __attribute__((ext_vector_type(4))) int i32x4;
typedef __attribute__((ext_vector_type(4))) float f32x4;

__device__ __forceinline__ void glds16(const uchar* g, uchar* l) {
    __builtin_amdgcn_global_load_lds(
        (const __attribute__((address_space(1))) unsigned int*)g,
        (__attribute__((address_space(3))) unsigned int*)l, 16, 0, 0);
}

// ---------------------------------------------------------------------------
// Kernel 1: L2-normalize rows, write fp8 e4m3 (OCP). Wave per row.
// ---------------------------------------------------------------------------
__global__ __launch_bounds__(256) void k_normalize(
    const float* __restrict__ tf, const float* __restrict__ vf,
    uchar* __restrict__ tn, uchar* __restrict__ vn,
    float* __restrict__ reg_sum) {
    if (blockIdx.x == 0 && threadIdx.x == 0) *reg_sum = 0.0f;
    const int w = threadIdx.x >> 6, l = threadIdx.x & 63;
    const int row = blockIdx.x * 4 + w;
    const float* src;
    uchar* dst;
    if (row < BB * NT) {
        src = tf + (size_t)row * DD;
        dst = tn + (size_t)row * DD;
    } else {
        int r = row - BB * NT;
        src = vf + (size_t)r * DD;
        dst = vn + (size_t)r * DD;
    }
    float4 x0 = ((const float4*)src)[l * 2];
    float4 x1 = ((const float4*)src)[l * 2 + 1];
    float ss = x0.x * x0.x + x0.y * x0.y + x0.z * x0.z + x0.w * x0.w
             + x1.x * x1.x + x1.y * x1.y + x1.z * x1.z + x1.w * x1.w;
    #pragma unroll
    for (int off = 32; off; off >>= 1) ss += __shfl_xor(ss, off, 64);
    float scale = 1.0f / fmaxf(sqrtf(ss), 1e-12f);
    int p0 = __builtin_amdgcn_cvt_pk_fp8_f32(x0.x * scale, x0.y * scale, 0, 0);
    p0 = __builtin_amdgcn_cvt_pk_fp8_f32(x0.z * scale, x0.w * scale, p0, 1);
    int p1 = __builtin_amdgcn_cvt_pk_fp8_f32(x1.x * scale, x1.y * scale, 0, 0);
    p1 = __builtin_amdgcn_cvt_pk_fp8_f32(x1.z * scale, x1.w * scale, p1, 1);
    ((uint2*)dst)[l] = make_uint2((unsigned)p0, (unsigned)p1);
}

// ---------------------------------------------------------------------------
// Kernel 2: 128x256 tile per (i,j) pair (round-4 verified geometry), with:
//   * V staged via global_load_lds into a 2x32KB double buffer (rotation
//     swizzle, verified) -- V is the operand with 2x cross-wave reuse AND
//     the one whose staging the barrier must fence anyway.
//   * T fragments loaded DIRECTLY global->VGPR (the round-6 CORRECTNESS-
//     verified direct formula, applied to wr): two global_load_dwordx4 at
//     trow*512 + kk + q*32. T slice/step = 16 KB (L1-friendly, 4x dup
//     absorbed by L1/L2); T loads are plain VMEM consumed by MFMA -- no
//     barrier coupling.
//   * LDS 98 -> 66 KB  =>  2 blocks/CU  =>  4 waves/SIMD: block A's barrier
//     drain + staging latency hides under block B's MFMAs.
//   * __launch_bounds__(512,2): the ONLY register config proven spill-free
//     (VGPR=128, WRITE~5MB in R0/R4; every other bound spilled ~610B/thr).
//     Register pressure here is strictly LOWER than R4 (a_b0/a_b1/t_off and
//     T-DMA addressing removed; one base pointer added).
// Schedule: prefetch-before-compute + one __syncthreads per K-step
// (correctness-verified rounds 2-6, absmax 0.0).
// ---------------------------------------------------------------------------
__global__ __launch_bounds__(512, 2) void k_gemm(
    const uchar* __restrict__ tn, const uchar* __restrict__ vn,
    const int* __restrict__ mask,
    float* __restrict__ clip_sims, float* __restrict__ reg_sum) {
    __shared__ uchar sV0[NV * BKB];   // 32 KB
    __shared__ uchar sV1[NV * BKB];   // 32 KB
    __shared__ float maxbuf[NT][4];   // row-max partials per wave col-group
    __shared__ float redw[8];
    __shared__ float c0[2], c1[2];

    // XCD-aware mapping (bijective over 4096 blocks), round-3/4 verified
    // locality: j fast over 8 private visual batches per XCD (V stays
    // L2-resident), i slow.
    const int bid = blockIdx.x;
    const int xcd = bid & 7;
    const int seq = bid >> 3;
    const int i = seq >> 3;              // text batch (0..63)
    const int j = xcd * 8 + (seq & 7);   // visual batch (0..63)

    const int tid = threadIdx.x;
    const int l = tid & 63, w = tid >> 6;
    const int wr = w >> 2, wc = w & 3;      // wave row-group (0..1), col-group (0..3)
    const int m15 = l & 15, q = l >> 4;

    const uchar* tbase = tn + (size_t)i * NT * DD;
    const uchar* vbase = vn + (size_t)j * NV * DD;

    // V staging: 16B unit f -> row r = f>>3, phys granule p = f&7 holds
    // logical granule g = (p - r) & 7.  src = r*DD + kk + g*16.
    int v_off[4];
    #pragma unroll
    for (int s = 0; s < 4; ++s) {
        int f = s * 512 + tid;
        int r = f >> 3, p = f & 7, g = (p - r) & 7;
        v_off[s] = r * DD + g * 16;
    }

    // B-fragment LDS read addresses (rotation-mirrored, verified):
    // lane holds k = q*32..q*32+31 of row wc*64+ct*16+m15.
    int b_b0[4], b_b1[4];
    #pragma unroll
    for (int ct = 0; ct < 4; ++ct) {
        int row = wc * 64 + ct * 16 + m15;
        b_b0[ct] = row * BKB + (((2 * q + row) & 7) * 16);
        b_b1[ct] = row * BKB + (((2 * q + 1 + row) & 7) * 16);
    }

    // A-fragment global base: row wr*64 + rt*16 + m15, k-bytes q*32..+31.
    // rt adds a static 16*DD; kk added per step. (Direct-load formula
    // correctness-verified in round 6.)
    const uchar* tptr = tbase + (size_t)((wr * 64 + m15) * DD + q * 32);

    f32x4 acc[4][4];
    #pragma unroll
    for (int rt = 0; rt < 4; ++rt)
        #pragma unroll
        for (int ct = 0; ct < 4; ++ct) acc[rt][ct] = (f32x4){0.f, 0.f, 0.f, 0.f};

    auto stage = [&](uchar* dV, int kk) {
        #pragma unroll
        for (int s = 0; s < 4; ++s)
            glds16(vbase + v_off[s] + kk, dV + (s * 512 + tid) * 16);
    };
    auto compute = [&](const uchar* bV, int kk) {
        i32x8 bf[4];
        #pragma unroll
        for (int ct = 0; ct < 4; ++ct) {
            i32x4 lo = *(const i32x4*)(bV + b_b0[ct]);
            i32x4 hi = *(const i32x4*)(bV + b_b1[ct]);
            bf[ct] = (i32x8){lo.x, lo.y, lo.z, lo.w, hi.x, hi.y, hi.z, hi.w};
        }
        #pragma unroll
        for (int rt = 0; rt < 4; ++rt) {
            const uchar* tp = tptr + rt * (16 * DD) + kk;
            i32x4 lo = *(const i32x4*)(tp);
            i32x4 hi = *(const i32x4*)(tp + 16);
            i32x8 a = (i32x8){lo.x, lo.y, lo.z, lo.w, hi.x, hi.y, hi.z, hi.w};
            #pragma unroll
            for (int ct = 0; ct < 4; ++ct)
                acc[rt][ct] = __builtin_amdgcn_mfma_scale_f32_16x16x128_f8f6f4(
                    a, bf[ct], acc[rt][ct],
                    0 /*A fmt=fp8*/, 0 /*B fmt=fp8*/,
                    0, 127 /*scaleA=1.0*/, 0, 127 /*scaleB=1.0*/);
        }
    };

    // Pipelined schedule: stage(next V) issued before compute(cur); one
    // barrier per K-step fences the prefetch drain and the buffer swap.
    stage(sV0, 0);
    __syncthreads();

    stage(sV1, 1 * BKB);
    compute(sV0, 0);
    __syncthreads();

    stage(sV0, 2 * BKB);
    compute(sV1, 1 * BKB);
    __syncthreads();

    stage(sV1, 3 * BKB);
    compute(sV0, 2 * BKB);
    __syncthreads();

    compute(sV1, 3 * BKB);

    // Epilogue 1: reg partial = sum of min(s,0)^2 over this lane's 64 values.
    float rp = 0.0f;
    #pragma unroll
    for (int rt = 0; rt < 4; ++rt)
        #pragma unroll
        for (int ct = 0; ct < 4; ++ct)
            #pragma unroll
            for (int r = 0; r < 4; ++r) {
                float m = fminf(acc[rt][ct][r], 0.0f);
                rp = fmaf(m, m, rp);
            }

    // Epilogue 2: row max. C/D layout: col = lane&15, row = q*4 + reg.
    #pragma unroll
    for (int rt = 0; rt < 4; ++rt)
        #pragma unroll
        for (int r = 0; r < 4; ++r) {
            float m = acc[rt][0][r];
            #pragma unroll
            for (int ct = 1; ct < 4; ++ct) m = fmaxf(m, acc[rt][ct][r]);
            #pragma unroll
            for (int msk = 1; msk < 16; msk <<= 1)
                m = fmaxf(m, __shfl_xor(m, msk, 64));
            if (m15 == 0)
                maxbuf[wr * 64 + rt * 16 + q * 4 + r][wc] = m;
        }

    #pragma unroll
    for (int off = 32; off; off >>= 1) rp += __shfl_down(rp, off, 64);
    if (l == 0) redw[w] = rp;
    __syncthreads();

    // Fused clip: masked mean of row maxes over the 128 text tokens.
    if (tid < NT) {
        float rm = fmaxf(fmaxf(maxbuf[tid][0], maxbuf[tid][1]),
                         fmaxf(maxbuf[tid][2], maxbuf[tid][3]));
        float mf = (float)mask[i * NT + tid];
        float v = rm * mf;
        #pragma unroll
        for (int off = 32; off; off >>= 1) {
            v += __shfl_down(v, off, 64);
            mf += __shfl_down(mf, off, 64);
        }
        if (l == 0) { c0[w] = v; c1[w] = mf; }
    }
    __syncthreads();
    if (tid == 0) {
        clip_sims[i * BB + j] = (c0[0] + c0[1]) / fmaxf(c1[0] + c1[1], EPSF);
        float s = 0.0f;
        #pragma unroll
        for (int x2 = 0; x2 < 8; ++x2) s += redw[x2];
        atomicAdd(reg_sum, s);
    }
}

// ---------------------------------------------------------------------------
// Kernel 3: final scalar loss. Single block, 256 threads.
// ---------------------------------------------------------------------------
__global__ __launch_bounds__(256) void k_loss(
    const float* __restrict__ clip_sims, const float* __restrict__ reg_sum,
    float* __restrict__ out) {
    __shared__ float sc[BB][BB + 1];
    __shared__ float lrow[BB], lcol[BB];
    int tid = threadIdx.x;
    for (int idx = tid; idx < BB * BB; idx += 256)
        sc[idx / BB][idx % BB] = clip_sims[idx];
    __syncthreads();
    if (tid < BB) {
        int i = tid;
        float m = sc[i][0];
        #pragma unroll
        for (int j = 1; j < BB; ++j) m = fmaxf(m, sc[i][j]);
        float s = 0.0f;
        #pragma unroll
        for (int j = 0; j < BB; ++j) s += expf(sc[i][j] - m);
        lrow[i] = m + logf(s) - sc[i][i];
    } else if (tid < 2 * BB) {
        int i = tid - BB;
        float m = sc[0][i];
        #pragma unroll
        for (int j = 1; j < BB; ++j) m = fmaxf(m, sc[j][i]);
        float s = 0.0f;
        #pragma unroll
        for (int j = 0; j < BB; ++j) s += expf(sc[j][i] - m);
        lcol[i] = m + logf(s) - sc[i][i];
    }
    __syncthreads();
    if (tid == 0) {
        float tot = 0.0f;
        for (int i = 0; i < BB; ++i) tot += lrow[i] + lcol[i];
        float contrastive = tot / (2.0f * BB);
        double denom = (double)BB * BB * NT * NV;  // 134217728
        float reg = 0.15f * (float)((double)reg_sum[0] / denom);
        out[0] = contrastive + reg;
    }
}

// ---------------------------------------------------------------------------
extern "C" void kernel_launch(void* const* d_in, const int* in_sizes, int n_in,
                              void* d_out, int out_size, void* d_ws, size_t ws_size,
                              hipStream_t stream) {
    const float* tf = (const float*)d_in[0];   // (B, NT, D) fp32
    const float* vf = (const float*)d_in[1];   // (B, NV, D) fp32
    const int* mask = (const int*)d_in[2];     // (B, NT) int32
    float* out = (float*)d_out;                // scalar fp32

    char* ws = (char*)d_ws;
    size_t tn_bytes = (size_t)BB * NT * DD;              // 4 MB fp8
    size_t vn_bytes = (size_t)BB * NV * DD;              // 8 MB fp8
    size_t cs_bytes = (size_t)BB * BB * sizeof(float);   // 16 KB

    uchar* tn = (uchar*)ws;
    uchar* vn = (uchar*)(ws + tn_bytes);
    float* clip_sims = (float*)(ws + tn_bytes + vn_bytes);
    float* reg_sum = (float*)(ws + tn_bytes + vn_bytes + cs_bytes);

    k_normalize<<<(BB * NT + BB * NV) / 4, 256, 0, stream>>>(tf, vf, tn, vn, reg_sum);
    k_gemm<<<BB * BB, 512, 0, stream>>>(tn, vn, mask, clip_sims, reg_sum);
    k_loss<<<1, 256, 0, stream>>>(clip_sims, reg_sum, out);
}

// Round 8
// 230.351 us; speedup vs baseline: 3.2015x; 1.3014x over previous
//
#include <hip/hip_runtime.h>
#include <hip/hip_bf16.h>

// Problem constants
#define BB 64     // batch
#define NT 128    // text tokens
#define NV 256    // visual tokens
#define DD 512    // feature dim (bytes per row in fp8)
#define BKB 128   // K-chunk in bytes: one 16x16x128 f8f6f4 k-step
#define EPSF 1e-7f

typedef __attribute__((ext_vector_type(8))) int i32x8;
typedef __attribute__((ext_vector_type(4))) int i32x4;
typedef __attribute__((ext_vector_type(4))) float f32x4;

__device__ __forceinline__ void glds16(const uchar* g, uchar* l) {
    __builtin_amdgcn_global_load_lds(
        (const __attribute__((address_space(1))) unsigned int*)g,
        (__attribute__((address_space(3))) unsigned int*)l, 16, 0, 0);
}

// ---------------------------------------------------------------------------
// Kernel 1: L2-normalize rows, write fp8 e4m3 (OCP). Wave per row.
// ---------------------------------------------------------------------------
__global__ __launch_bounds__(256) void k_normalize(
    const float* __restrict__ tf, const float* __restrict__ vf,
    uchar* __restrict__ tn, uchar* __restrict__ vn,
    float* __restrict__ reg_sum) {
    if (blockIdx.x == 0 && threadIdx.x == 0) *reg_sum = 0.0f;
    const int w = threadIdx.x >> 6, l = threadIdx.x & 63;
    const int row = blockIdx.x * 4 + w;
    const float* src;
    uchar* dst;
    if (row < BB * NT) {
        src = tf + (size_t)row * DD;
        dst = tn + (size_t)row * DD;
    } else {
        int r = row - BB * NT;
        src = vf + (size_t)r * DD;
        dst = vn + (size_t)r * DD;
    }
    float4 x0 = ((const float4*)src)[l * 2];
    float4 x1 = ((const float4*)src)[l * 2 + 1];
    float ss = x0.x * x0.x + x0.y * x0.y + x0.z * x0.z + x0.w * x0.w
             + x1.x * x1.x + x1.y * x1.y + x1.z * x1.z + x1.w * x1.w;
    #pragma unroll
    for (int off = 32; off; off >>= 1) ss += __shfl_xor(ss, off, 64);
    float scale = 1.0f / fmaxf(sqrtf(ss), 1e-12f);
    int p0 = __builtin_amdgcn_cvt_pk_fp8_f32(x0.x * scale, x0.y * scale, 0, 0);
    p0 = __builtin_amdgcn_cvt_pk_fp8_f32(x0.z * scale, x0.w * scale, p0, 1);
    int p1 = __builtin_amdgcn_cvt_pk_fp8_f32(x1.x * scale, x1.y * scale, 0, 0);
    p1 = __builtin_amdgcn_cvt_pk_fp8_f32(x1.z * scale, x1.w * scale, p1, 1);
    ((uint2*)dst)[l] = make_uint2((unsigned)p0, (unsigned)p1);
}

// ---------------------------------------------------------------------------
// Kernel 2: ROUND-4 kernel verbatim (128x256 tile, T+V LDS DMA double-buffer,
// acc[4][4], VGPR=128 proven spill-free, 151us) with ONE change: the
// schedule is deepened from 1-ahead/drain-vmcnt(0) to 2-AHEAD prefetch with
// COUNTED vmcnt (T4). Old schedule: stage(k+1); compute(k); __syncthreads
// [= s_waitcnt vmcnt(0): waits for the JUST-ISSUED k+1 loads -> prefetch
// gets only ~1100cy of cover]. New schedule: tiles k and k+1 both in
// flight; before compute(k): s_waitcnt vmcnt(6) [retires exactly tile k's
// 6 loads per wave, FIFO] + s_barrier; after compute(k): s_barrier [all
// waves done reading buf k&1] then re-stage it with tile k+2. Each tile
// now has ~2 compute-phases (~2200cy) to land and the newest loads are
// never waited on mid-loop.
// Correctness: all ds_read data is consumed by MFMAs (data dep) before the
// consume-barrier; buffers re-staged only after it; all 512 threads run
// identical barrier sequences; vmcnt FIFO semantics per guide m135.
// ---------------------------------------------------------------------------
__global__ __launch_bounds__(512, 2) void k_gemm(
    const uchar* __restrict__ tn, const uchar* __restrict__ vn,
    const int* __restrict__ mask,
    float* __restrict__ clip_sims, float* __restrict__ reg_sum) {
    __shared__ uchar sT0[NT * BKB];   // 16 KB
    __shared__ uchar sT1[NT * BKB];   // 16 KB
    __shared__ uchar sV0[NV * BKB];   // 32 KB
    __shared__ uchar sV1[NV * BKB];   // 32 KB
    __shared__ float maxbuf[NT][4];   // row-max partials per wave col-group
    __shared__ float redw[8];
    __shared__ float c0[2], c1[2];

    const int i = blockIdx.x, j = blockIdx.y;
    const int tid = threadIdx.x;
    const int l = tid & 63, w = tid >> 6;
    const int wr = w >> 2, wc = w & 3;      // wave row-group (0..1), col-group (0..3)
    const int m15 = l & 15, q = l >> 4;

    const uchar* tbase = tn + (size_t)i * NT * DD;
    const uchar* vbase = vn + (size_t)j * NV * DD;

    // Staging: 16B unit f -> row r = f>>3, phys granule p = f&7 holds
    // logical granule g = (p - r) & 7.  src = r*DD + kk + g*16.
    int t_off[2], v_off[4];
    #pragma unroll
    for (int s = 0; s < 2; ++s) {
        int f = s * 512 + tid;
        int r = f >> 3, p = f & 7, g = (p - r) & 7;
        t_off[s] = r * DD + g * 16;
    }
    #pragma unroll
    for (int s = 0; s < 4; ++s) {
        int f = s * 512 + tid;
        int r = f >> 3, p = f & 7, g = (p - r) & 7;
        v_off[s] = r * DD + g * 16;
    }

    // Fragment read addresses: lane holds k = q*32..q*32+31 of its row,
    // logical granules 2q, 2q+1 -> phys (2q+row)&7, (2q+1+row)&7.
    int a_b0[4], a_b1[4], b_b0[4], b_b1[4];
    #pragma unroll
    for (int rt = 0; rt < 4; ++rt) {
        int row = wr * 64 + rt * 16 + m15;
        a_b0[rt] = row * BKB + (((2 * q + row) & 7) * 16);
        a_b1[rt] = row * BKB + (((2 * q + 1 + row) & 7) * 16);
    }
    #pragma unroll
    for (int ct = 0; ct < 4; ++ct) {
        int row = wc * 64 + ct * 16 + m15;
        b_b0[ct] = row * BKB + (((2 * q + row) & 7) * 16);
        b_b1[ct] = row * BKB + (((2 * q + 1 + row) & 7) * 16);
    }

    f32x4 acc[4][4];
    #pragma unroll
    for (int rt = 0; rt < 4; ++rt)
        #pragma unroll
        for (int ct = 0; ct < 4; ++ct) acc[rt][ct] = (f32x4){0.f, 0.f, 0.f, 0.f};

    auto stage = [&](uchar* dT, uchar* dV, int kk) {
        #pragma unroll
        for (int s = 0; s < 2; ++s)
            glds16(tbase + t_off[s] + kk, dT + (s * 512 + tid) * 16);
        #pragma unroll
        for (int s = 0; s < 4; ++s)
            glds16(vbase + v_off[s] + kk, dV + (s * 512 + tid) * 16);
    };
    auto compute = [&](const uchar* bT, const uchar* bV) {
        i32x8 bf[4];
        #pragma unroll
        for (int ct = 0; ct < 4; ++ct) {
            i32x4 lo = *(const i32x4*)(bV + b_b0[ct]);
            i32x4 hi = *(const i32x4*)(bV + b_b1[ct]);
            bf[ct] = (i32x8){lo.x, lo.y, lo.z, lo.w, hi.x, hi.y, hi.z, hi.w};
        }
        #pragma unroll
        for (int rt = 0; rt < 4; ++rt) {
            i32x4 lo = *(const i32x4*)(bT + a_b0[rt]);
            i32x4 hi = *(const i32x4*)(bT + a_b1[rt]);
            i32x8 a = (i32x8){lo.x, lo.y, lo.z, lo.w, hi.x, hi.y, hi.z, hi.w};
            #pragma unroll
            for (int ct = 0; ct < 4; ++ct)
                acc[rt][ct] = __builtin_amdgcn_mfma_scale_f32_16x16x128_f8f6f4(
                    a, bf[ct], acc[rt][ct],
                    0 /*A fmt=fp8*/, 0 /*B fmt=fp8*/,
                    0, 127 /*scaleA=1.0*/, 0, 127 /*scaleB=1.0*/);
        }
    };

    // --- 2-deep pipelined schedule with counted vmcnt ---------------------
    // Outstanding DMA per wave is always {oldest tile: 6, newest tile: 6}.
    stage(sT0, sV0, 0);          // tile 0 -> 6 outstanding
    stage(sT1, sV1, 1 * BKB);    // tile 1 -> 12 outstanding

    // ks = 0
    asm volatile("s_waitcnt vmcnt(6)" ::: "memory");   // tile 0 landed
    __builtin_amdgcn_s_barrier();
    asm volatile("" ::: "memory");
    compute(sT0, sV0);
    asm volatile("" ::: "memory");
    __builtin_amdgcn_s_barrier();                      // all done reading buf0
    stage(sT0, sV0, 2 * BKB);    // tile 2 -> 12 outstanding

    // ks = 1
    asm volatile("s_waitcnt vmcnt(6)" ::: "memory");   // tile 1 landed
    __builtin_amdgcn_s_barrier();
    asm volatile("" ::: "memory");
    compute(sT1, sV1);
    asm volatile("" ::: "memory");
    __builtin_amdgcn_s_barrier();                      // all done reading buf1
    stage(sT1, sV1, 3 * BKB);    // tile 3 -> 12 outstanding

    // ks = 2
    asm volatile("s_waitcnt vmcnt(6)" ::: "memory");   // tile 2 landed
    __builtin_amdgcn_s_barrier();
    asm volatile("" ::: "memory");
    compute(sT0, sV0);
    asm volatile("" ::: "memory");
    __builtin_amdgcn_s_barrier();

    // ks = 3
    asm volatile("s_waitcnt vmcnt(0)" ::: "memory");   // tile 3 landed
    __builtin_amdgcn_s_barrier();
    asm volatile("" ::: "memory");
    compute(sT1, sV1);

    // Epilogue 1: reg partial = sum of min(s,0)^2 over this lane's 64 values.
    float rp = 0.0f;
    #pragma unroll
    for (int rt = 0; rt < 4; ++rt)
        #pragma unroll
        for (int ct = 0; ct < 4; ++ct)
            #pragma unroll
            for (int r = 0; r < 4; ++r) {
                float m = fminf(acc[rt][ct][r], 0.0f);
                rp = fmaf(m, m, rp);
            }

    // Epilogue 2: row max. C/D layout: col = lane&15, row = q*4 + reg.
    #pragma unroll
    for (int rt = 0; rt < 4; ++rt)
        #pragma unroll
        for (int r = 0; r < 4; ++r) {
            float m = acc[rt][0][r];
            #pragma unroll
            for (int ct = 1; ct < 4; ++ct) m = fmaxf(m, acc[rt][ct][r]);
            #pragma unroll
            for (int msk = 1; msk < 16; msk <<= 1)
                m = fmaxf(m, __shfl_xor(m, msk, 64));
            if (m15 == 0)
                maxbuf[wr * 64 + rt * 16 + q * 4 + r][wc] = m;
        }

    #pragma unroll
    for (int off = 32; off; off >>= 1) rp += __shfl_down(rp, off, 64);
    if (l == 0) redw[w] = rp;
    __syncthreads();

    // Fused clip: masked mean of row maxes over the 128 text tokens.
    if (tid < NT) {
        float rm = fmaxf(fmaxf(maxbuf[tid][0], maxbuf[tid][1]),
                         fmaxf(maxbuf[tid][2], maxbuf[tid][3]));
        float mf = (float)mask[i * NT + tid];
        float v = rm * mf;
        #pragma unroll
        for (int off = 32; off; off >>= 1) {
            v += __shfl_down(v, off, 64);
            mf += __shfl_down(mf, off, 64);
        }
        if (l == 0) { c0[w] = v; c1[w] = mf; }
    }
    __syncthreads();
    if (tid == 0) {
        clip_sims[i * BB + j] = (c0[0] + c0[1]) / fmaxf(c1[0] + c1[1], EPSF);
        float s = 0.0f;
        #pragma unroll
        for (int x = 0; x < 8; ++x) s += redw[x];
        atomicAdd(reg_sum, s);
    }
}

// ---------------------------------------------------------------------------
// Kernel 3: final scalar loss. Single block, 256 threads.
// ---------------------------------------------------------------------------
__global__ __launch_bounds__(256) void k_loss(
    const float* __restrict__ clip_sims, const float* __restrict__ reg_sum,
    float* __restrict__ out) {
    __shared__ float sc[BB][BB + 1];
    __shared__ float lrow[BB], lcol[BB];
    int tid = threadIdx.x;
    for (int idx = tid; idx < BB * BB; idx += 256)
        sc[idx / BB][idx % BB] = clip_sims[idx];
    __syncthreads();
    if (tid < BB) {
        int i = tid;
        float m = sc[i][0];
        #pragma unroll
        for (int j = 1; j < BB; ++j) m = fmaxf(m, sc[i][j]);
        float s = 0.0f;
        #pragma unroll
        for (int j = 0; j < BB; ++j) s += expf(sc[i][j] - m);
        lrow[i] = m + logf(s) - sc[i][i];
    } else if (tid < 2 * BB) {
        int i = tid - BB;
        float m = sc[0][i];
        #pragma unroll
        for (int j = 1; j < BB; ++j) m = fmaxf(m, sc[j][i]);
        float s = 0.0f;
        #pragma unroll
        for (int j = 0; j < BB; ++j) s += expf(sc[j][i] - m);
        lcol[i] = m + logf(s) - sc[i][i];
    }
    __syncthreads();
    if (tid == 0) {
        float tot = 0.0f;
        for (int i = 0; i < BB; ++i) tot += lrow[i] + lcol[i];
        float contrastive = tot / (2.0f * BB);
        double denom = (double)BB * BB * NT * NV;  // 134217728
        float reg = 0.15f * (float)((double)reg_sum[0] / denom);
        out[0] = contrastive + reg;
    }
}

// ---------------------------------------------------------------------------
extern "C" void kernel_launch(void* const* d_in, const int* in_sizes, int n_in,
                              void* d_out, int out_size, void* d_ws, size_t ws_size,
                              hipStream_t stream) {
    const float* tf = (const float*)d_in[0];   // (B, NT, D) fp32
    const float* vf = (const float*)d_in[1];   // (B, NV, D) fp32
    const int* mask = (const int*)d_in[2];     // (B, NT) int32
    float* out = (float*)d_out;                // scalar fp32

    char* ws = (char*)d_ws;
    size_t tn_bytes = (size_t)BB * NT * DD;              // 4 MB fp8
    size_t vn_bytes = (size_t)BB * NV * DD;              // 8 MB fp8
    size_t cs_bytes = (size_t)BB * BB * sizeof(float);   // 16 KB

    uchar* tn = (uchar*)ws;
    uchar* vn = (uchar*)(ws + tn_bytes);
    float* clip_sims = (float*)(ws + tn_bytes + vn_bytes);
    float* reg_sum = (float*)(ws + tn_bytes + vn_bytes + cs_bytes);

    k_normalize<<<(BB * NT + BB * NV) / 4, 256, 0, stream>>>(tf, vf, tn, vn, reg_sum);
    k_gemm<<<dim3(BB, BB), 512, 0, stream>>>(tn, vn, mask, clip_sims, reg_sum);
    k_loss<<<1, 256, 0, stream>>>(clip_sims, reg_sum, out);
}